// Round 14
// baseline (135.172 us; speedup 1.0000x reference)
//
#include <hip/hip_runtime.h>

#define NN 50000
#define NE 800000
#define NG 256
#define NB 256        // buckets
#define BW 196        // nodes per bucket
#define NBIN 200      // bin virtual blocks
#define EPB 4000      // edges per bin block: NBIN*EPB == NE
#define NGEMM 391     // gemm1 blocks: (NN+127)/128
#define PAD 16        // ints: pad hot atomics to one 64B line
#define CAP 4608      // fixed region per bucket (mean 3136, +26 sigma)
#define WT_STRIDE 136 // LDS W-tile row stride in bf16

typedef __attribute__((ext_vector_type(8))) short bf16x8;
typedef __attribute__((ext_vector_type(4))) float f32x4;
typedef __attribute__((ext_vector_type(2))) float f32x2;

static __device__ __forceinline__ unsigned short f2b(float f) {
    unsigned int u = __float_as_uint(f);
    return (unsigned short)((u + 0x7FFFu + ((u >> 16) & 1u)) >> 16);
}

// 1) FUSED front kernel, 512 threads/block (8 waves/CU — round-11 win).
//    blocks [0, NGEMM): h8 = fp8(x @ W1), each wave owns ONE 16-row tile.
//    blocks [NGEMM, ...): bin edges into ebuf regions (stride-512 loops).
//    h8 byte layout PERMUTED: byte (lid*8+jt) of row gr = col (jt*16+lid).
__global__ __launch_bounds__(512) void k_front(const float* __restrict__ x,
                                               const float* __restrict__ W,
                                               unsigned char* __restrict__ h8,
                                               const int* __restrict__ src,
                                               const int* __restrict__ dst,
                                               int* __restrict__ bcur,
                                               unsigned int* __restrict__ ebuf) {
    __shared__ __align__(16) unsigned short Ws[128 * WT_STRIDE]; // 34816 B union
    const int tid = threadIdx.x;

    if (blockIdx.x >= NGEMM) {
        // ---- binning path (first 3 KB of Ws as int scratch) ----
        int* lh = (int*)Ws;
        int* gb = lh + NB;
        int* lc = gb + NB;
        if (tid < NB) { lh[tid] = 0; lc[tid] = 0; }
        __syncthreads();
        int e0 = (blockIdx.x - NGEMM) * EPB;
        for (int i = e0 + tid; i < e0 + EPB; i += 512)
            atomicAdd(&lh[(unsigned)dst[i] / BW], 1);
        __syncthreads();
        if (tid < NB && lh[tid])
            gb[tid] = tid * CAP + atomicAdd(&bcur[tid * PAD], lh[tid]);
        __syncthreads();
        for (int i = e0 + tid; i < e0 + EPB; i += 512) {  // dst re-read hot
            int d = dst[i];
            int b = (unsigned)d / BW;
            int r = atomicAdd(&lc[b], 1);
            ebuf[gb[b] + r] = ((unsigned)(d - b * BW) << 17) | (unsigned)src[i];
        }
        return;
    }

    // ---- gemm1 path: h8(fp8) = x @ W1 (unscaled), MFMA 16x16x32 bf16 ----
#pragma unroll
    for (int p = 0; p < 32; ++p) {           // 512 thr x 32 = 16384 = 128x128
        int g = p * 512 + tid;
        int k = g >> 7, n = g & 127;         // coalesced read of W[k][n]
        Ws[n * WT_STRIDE + k] = f2b(W[g]);
    }
    __syncthreads();
    const int w = tid >> 6, lane = tid & 63; // w in [0,8): one 16-row tile/wave
    const int q = lane >> 4, lid = lane & 15;
    const int m0 = blockIdx.x * 128 + w * 16;
    const int m = m0 + lid;
    f32x4 acc[8];
#pragma unroll
    for (int jt = 0; jt < 8; ++jt) acc[jt] = (f32x4){0.f, 0.f, 0.f, 0.f};

#pragma unroll
    for (int kt = 0; kt < 4; ++kt) {
        bf16x8 a;
        {
            int k0 = kt * 32 + q * 8;
            float4 p0 = make_float4(0.f, 0.f, 0.f, 0.f), p1 = p0;
            if (m < NN) {
                p0 = *(const float4*)(x + (size_t)m * 128 + k0);
                p1 = *(const float4*)(x + (size_t)m * 128 + k0 + 4);
            }
            a[0] = (short)f2b(p0.x); a[1] = (short)f2b(p0.y);
            a[2] = (short)f2b(p0.z); a[3] = (short)f2b(p0.w);
            a[4] = (short)f2b(p1.x); a[5] = (short)f2b(p1.y);
            a[6] = (short)f2b(p1.z); a[7] = (short)f2b(p1.w);
        }
#pragma unroll
        for (int jt = 0; jt < 8; ++jt) {
            bf16x8 b = *(const bf16x8*)(Ws + (jt * 16 + lid) * WT_STRIDE + kt * 32 + q * 8);
            acc[jt] = __builtin_amdgcn_mfma_f32_16x16x32_bf16(a, b, acc[jt], 0, 0, 0);
        }
    }
    // epilogue: C/D layout col=lane&15, row=q*4+reg; pack 8 jt-values -> uint2
#pragma unroll
    for (int reg = 0; reg < 4; ++reg) {
        int gr = m0 + q * 4 + reg;
        if (gr < NN) {
            int d0 = __builtin_amdgcn_cvt_pk_fp8_f32(acc[0][reg], acc[1][reg], 0, false);
            d0 = __builtin_amdgcn_cvt_pk_fp8_f32(acc[2][reg], acc[3][reg], d0, true);
            int d1 = __builtin_amdgcn_cvt_pk_fp8_f32(acc[4][reg], acc[5][reg], 0, false);
            d1 = __builtin_amdgcn_cvt_pk_fp8_f32(acc[6][reg], acc[7][reg], d1, true);
            *(uint2*)(h8 + (size_t)gr * 128 + lid * 8) = make_uint2((unsigned)d0, (unsigned)d1);
        }
    }
}

// 2) per-bucket counting sort, 512 threads/block (round-12 version, verified).
__global__ __launch_bounds__(512) void k_sort(const unsigned int* __restrict__ ebuf,
                                              const int* __restrict__ bcur,
                                              int* __restrict__ csr_src,
                                              int* __restrict__ rowptr,
                                              int* __restrict__ deg,
                                              float* __restrict__ dinv) {
    __shared__ int hist[NB], off[NB], cur[NB];
    __shared__ int stage[CAP];
    const int t = threadIdx.x;
    const int b = blockIdx.x;
    const int cnt = bcur[b * PAD];
    const int ebeg = b * CAP;
    const int nbase = b * BW;
    if (t < NB) { hist[t] = 0; cur[t] = 0; }
    __syncthreads();
    for (int i = t; i < cnt; i += 512)
        atomicAdd(&hist[ebuf[ebeg + i] >> 17], 1);
    __syncthreads();
    int v = 0;
    if (t < NB) { v = hist[t]; off[t] = v; }
    __syncthreads();
    for (int o = 1; o < NB; o <<= 1) {
        int u = (t < NB && t >= o) ? off[t - o] : 0;
        __syncthreads();
        if (t < NB) off[t] += u;
        __syncthreads();
    }
    if (t < NB) {
        int ex = off[t] - v;
        int gn = nbase + t;
        if (t < BW && gn < NN) {
            rowptr[gn] = ebeg + ex;
            deg[gn] = v;
            dinv[gn] = rsqrtf((float)(v + 1));
        }
    }
    __syncthreads();
    if (t < NB) off[t] -= v;                 // exclusive prefix
    __syncthreads();
    for (int i = t; i < cnt; i += 512) {
        unsigned int p = ebuf[ebeg + i];
        int l = p >> 17;
        int r = atomicAdd(&cur[l], 1);
        stage[off[l] + r] = (int)(p & 0x1FFFFu);
    }
    __syncthreads();
    for (int i = t; i < cnt; i += 512)
        csr_src[ebeg + i] = stage[i];
}

// 3) aggregation, 512 threads/block: TWO 16-lane groups per dst node split the
//    edge list by parity — halves the dependent csr->h8 chain and doubles
//    independent chains (chain-latency-bound; round-5 showed not issue-bound).
//    Scale/bias/relu applied at the combine+pool stage. h8 permuted layout.
__global__ __launch_bounds__(512) void k_agg(const unsigned char* __restrict__ h8,
                                             const int* __restrict__ csr_src,
                                             const int* __restrict__ rowptr,
                                             const int* __restrict__ deg,
                                             const float* __restrict__ dinv,
                                             const float* __restrict__ b1,
                                             const int* __restrict__ batch,
                                             int* __restrict__ pooled) {
    const int tid = threadIdx.x;
    const int g = tid >> 4, ql = tid & 15;   // 32 groups
    const int nd = g >> 1, par = g & 1;      // node-in-block, edge parity
    const int n = blockIdx.x * 16 + nd;      // NN = 3125*16, no tail
    __shared__ float vals[2][16][128];
    __shared__ float dds[16];
    __shared__ int bts[16];
    if (ql == 0 && par == 0) { bts[nd] = batch[n]; dds[nd] = dinv[n]; }
    const int beg = rowptr[n];
    const int end = beg + deg[n];
    const int c = ql * 8;
    float a[8];
#pragma unroll
    for (int j = 0; j < 8; ++j) a[j] = 0.f;
#pragma unroll 4
    for (int i = beg + par; i < end; i += 2) {
        int s = csr_src[i];
        float ds = dinv[s];
        uint2 v = *(const uint2*)(h8 + (size_t)s * 128 + c);
        f32x2 f0 = __builtin_amdgcn_cvt_pk_f32_fp8((int)v.x, false);
        f32x2 f1 = __builtin_amdgcn_cvt_pk_f32_fp8((int)v.x, true);
        f32x2 f2 = __builtin_amdgcn_cvt_pk_f32_fp8((int)v.y, false);
        f32x2 f3 = __builtin_amdgcn_cvt_pk_f32_fp8((int)v.y, true);
        a[0] = fmaf(ds, f0.x, a[0]); a[1] = fmaf(ds, f0.y, a[1]);
        a[2] = fmaf(ds, f1.x, a[2]); a[3] = fmaf(ds, f1.y, a[3]);
        a[4] = fmaf(ds, f2.x, a[4]); a[5] = fmaf(ds, f2.y, a[5]);
        a[6] = fmaf(ds, f3.x, a[6]); a[7] = fmaf(ds, f3.y, a[7]);
    }
    if (par == 0) {
        // self loop: + dinv[n]*h[n] into the parity-0 partial
        float ddl = dinv[n];
        uint2 hv = *(const uint2*)(h8 + (size_t)n * 128 + c);
        f32x2 f0 = __builtin_amdgcn_cvt_pk_f32_fp8((int)hv.x, false);
        f32x2 f1 = __builtin_amdgcn_cvt_pk_f32_fp8((int)hv.x, true);
        f32x2 f2 = __builtin_amdgcn_cvt_pk_f32_fp8((int)hv.y, false);
        f32x2 f3 = __builtin_amdgcn_cvt_pk_f32_fp8((int)hv.y, true);
        a[0] = fmaf(ddl, f0.x, a[0]); a[1] = fmaf(ddl, f0.y, a[1]);
        a[2] = fmaf(ddl, f1.x, a[2]); a[3] = fmaf(ddl, f1.y, a[3]);
        a[4] = fmaf(ddl, f2.x, a[4]); a[5] = fmaf(ddl, f2.y, a[5]);
        a[6] = fmaf(ddl, f3.x, a[6]); a[7] = fmaf(ddl, f3.y, a[7]);
    }
    *(float4*)&vals[par][nd][c]     = make_float4(a[0], a[1], a[2], a[3]);
    *(float4*)&vals[par][nd][c + 4] = make_float4(a[4], a[5], a[6], a[7]);
    __syncthreads();
    if (tid < 128) {
        const int pcol = ((tid & 7) << 4) | (tid >> 3);  // un-permute channel
        const float bbt = b1[pcol];
        float m = fmaxf(dds[0] * (vals[0][0][tid] + vals[1][0][tid]) + bbt, 0.f);
        int cur = bts[0];
#pragma unroll
        for (int ww = 1; ww < 16; ++ww) {
            float r = fmaxf(dds[ww] * (vals[0][ww][tid] + vals[1][ww][tid]) + bbt, 0.f);
            if (bts[ww] != cur) {
                atomicMax(&pooled[cur * 128 + pcol], __float_as_int(m));
                cur = bts[ww];
                m = r;
            } else {
                m = fmaxf(m, r);
            }
        }
        atomicMax(&pooled[cur * 128 + pcol], __float_as_int(m));
    }
}

// 4) out = relu(pooled @ W2 + b2)
__global__ __launch_bounds__(256) void k_gemm2(const float* __restrict__ pooled,
                                               const float* __restrict__ W2,
                                               const float* __restrict__ b2,
                                               float* __restrict__ out) {
    const int tid = threadIdx.x;
    const int row = blockIdx.x * 4 + (tid >> 6);
    const int col = tid & 63;
    const float* p = pooled + row * 128;
    float acc = b2[col];
    for (int k = 0; k < 128; ++k) acc += p[k] * W2[k * 64 + col];
    out[row * 64 + col] = fmaxf(acc, 0.f);
}

extern "C" void kernel_launch(void* const* d_in, const int* in_sizes, int n_in,
                              void* d_out, int out_size, void* d_ws, size_t ws_size,
                              hipStream_t stream) {
    const float* x     = (const float*)d_in[0];
    const int*   ei    = (const int*)d_in[1];   // [2, NE]: src row then dst row
    const int*   batch = (const int*)d_in[2];
    const float* W1    = (const float*)d_in[3];
    const float* b1    = (const float*)d_in[4];
    const float* W2    = (const float*)d_in[5];
    const float* b2    = (const float*)d_in[6];
    float* out = (float*)d_out;

    // ws layout (int units) — IDENTICAL to round-12 passing run:
    // [zeroed: pooled NG*128 | bcur NB*PAD] rowptr NN | deg NN | dinv NN |
    // csr_src NB*CAP | ebuf NB*CAP | h8 NN*128 bytes
    int*   pooled  = (int*)d_ws;
    int*   bcur    = pooled + (size_t)NG * 128;
    int*   rowptr  = bcur + NB * PAD;
    int*   deg     = rowptr + NN;
    float* dinv    = (float*)(deg + NN);
    int*   csr_src = (int*)(dinv + NN);
    unsigned int* ebuf = (unsigned int*)(csr_src + (size_t)NB * CAP);
    unsigned char* h8  = (unsigned char*)(ebuf + (size_t)NB * CAP);

    size_t zbytes = ((size_t)NG * 128 + NB * PAD) * 4;
    hipMemsetAsync(d_ws, 0, zbytes, stream);

    const int* srcv = ei;
    const int* dstv = ei + NE;

    k_front<<<NGEMM + NBIN, 512, 0, stream>>>(x, W1, h8, srcv, dstv, bcur, ebuf);
    k_sort<<<NB, 512, 0, stream>>>(ebuf, bcur, csr_src, rowptr, deg, dinv);
    k_agg<<<NN / 16, 512, 0, stream>>>(h8, csr_src, rowptr, deg, dinv, b1, batch, pooled);
    k_gemm2<<<NG / 4, 256, 0, stream>>>((const float*)pooled, W2, b2, out);
}

// Round 15
// 129.409 us; speedup vs baseline: 1.0445x; 1.0445x over previous
//
#include <hip/hip_runtime.h>

#define NN 50000
#define NE 800000
#define NG 256
#define NB 256        // buckets
#define BW 196        // nodes per bucket
#define NBIN 200      // bin virtual blocks
#define EPB 4000      // edges per bin block: NBIN*EPB == NE
#define NGEMM 391     // gemm1 blocks: (NN+127)/128
#define PAD 16        // ints: pad hot atomics to one 64B line
#define CAP 4608      // fixed region per bucket (mean 3136, +26 sigma)
#define WT_STRIDE 136 // LDS W-tile row stride in bf16

typedef __attribute__((ext_vector_type(8))) short bf16x8;
typedef __attribute__((ext_vector_type(4))) float f32x4;
typedef __attribute__((ext_vector_type(2))) float f32x2;

static __device__ __forceinline__ unsigned short f2b(float f) {
    unsigned int u = __float_as_uint(f);
    return (unsigned short)((u + 0x7FFFu + ((u >> 16) & 1u)) >> 16);
}

// 1) FUSED front kernel, 512 threads/block (8 waves/CU — the round-11 win).
//    blocks [0, NGEMM): h8 = fp8(x @ W1), each wave owns ONE 16-row tile.
//    blocks [NGEMM, ...): bin edges into ebuf regions (stride-512 loops).
//    h8 byte layout PERMUTED: byte (lid*8+jt) of row gr = col (jt*16+lid)
//    -> one uint2 store per row-slice.
__global__ __launch_bounds__(512) void k_front(const float* __restrict__ x,
                                               const float* __restrict__ W,
                                               unsigned char* __restrict__ h8,
                                               const int* __restrict__ src,
                                               const int* __restrict__ dst,
                                               int* __restrict__ bcur,
                                               unsigned int* __restrict__ ebuf) {
    __shared__ __align__(16) unsigned short Ws[128 * WT_STRIDE]; // 34816 B union
    const int tid = threadIdx.x;

    if (blockIdx.x >= NGEMM) {
        // ---- binning path (first 3 KB of Ws as int scratch) ----
        int* lh = (int*)Ws;
        int* gb = lh + NB;
        int* lc = gb + NB;
        if (tid < NB) { lh[tid] = 0; lc[tid] = 0; }
        __syncthreads();
        int e0 = (blockIdx.x - NGEMM) * EPB;
        for (int i = e0 + tid; i < e0 + EPB; i += 512)
            atomicAdd(&lh[(unsigned)dst[i] / BW], 1);
        __syncthreads();
        if (tid < NB && lh[tid])
            gb[tid] = tid * CAP + atomicAdd(&bcur[tid * PAD], lh[tid]);
        __syncthreads();
        for (int i = e0 + tid; i < e0 + EPB; i += 512) {  // dst re-read hot
            int d = dst[i];
            int b = (unsigned)d / BW;
            int r = atomicAdd(&lc[b], 1);
            ebuf[gb[b] + r] = ((unsigned)(d - b * BW) << 17) | (unsigned)src[i];
        }
        return;
    }

    // ---- gemm1 path: h8(fp8) = x @ W1 (unscaled), MFMA 16x16x32 bf16 ----
#pragma unroll
    for (int p = 0; p < 32; ++p) {           // 512 thr x 32 = 16384 = 128x128
        int g = p * 512 + tid;
        int k = g >> 7, n = g & 127;         // coalesced read of W[k][n]
        Ws[n * WT_STRIDE + k] = f2b(W[g]);
    }
    __syncthreads();
    const int w = tid >> 6, lane = tid & 63; // w in [0,8): one 16-row tile/wave
    const int q = lane >> 4, lid = lane & 15;
    const int m0 = blockIdx.x * 128 + w * 16;
    const int m = m0 + lid;
    f32x4 acc[8];
#pragma unroll
    for (int jt = 0; jt < 8; ++jt) acc[jt] = (f32x4){0.f, 0.f, 0.f, 0.f};

#pragma unroll
    for (int kt = 0; kt < 4; ++kt) {
        bf16x8 a;
        {
            int k0 = kt * 32 + q * 8;
            float4 p0 = make_float4(0.f, 0.f, 0.f, 0.f), p1 = p0;
            if (m < NN) {
                p0 = *(const float4*)(x + (size_t)m * 128 + k0);
                p1 = *(const float4*)(x + (size_t)m * 128 + k0 + 4);
            }
            a[0] = (short)f2b(p0.x); a[1] = (short)f2b(p0.y);
            a[2] = (short)f2b(p0.z); a[3] = (short)f2b(p0.w);
            a[4] = (short)f2b(p1.x); a[5] = (short)f2b(p1.y);
            a[6] = (short)f2b(p1.z); a[7] = (short)f2b(p1.w);
        }
#pragma unroll
        for (int jt = 0; jt < 8; ++jt) {
            bf16x8 b = *(const bf16x8*)(Ws + (jt * 16 + lid) * WT_STRIDE + kt * 32 + q * 8);
            acc[jt] = __builtin_amdgcn_mfma_f32_16x16x32_bf16(a, b, acc[jt], 0, 0, 0);
        }
    }
    // epilogue: C/D layout col=lane&15, row=q*4+reg; pack 8 jt-values -> uint2
#pragma unroll
    for (int reg = 0; reg < 4; ++reg) {
        int gr = m0 + q * 4 + reg;
        if (gr < NN) {
            int d0 = __builtin_amdgcn_cvt_pk_fp8_f32(acc[0][reg], acc[1][reg], 0, false);
            d0 = __builtin_amdgcn_cvt_pk_fp8_f32(acc[2][reg], acc[3][reg], d0, true);
            int d1 = __builtin_amdgcn_cvt_pk_fp8_f32(acc[4][reg], acc[5][reg], 0, false);
            d1 = __builtin_amdgcn_cvt_pk_fp8_f32(acc[6][reg], acc[7][reg], d1, true);
            *(uint2*)(h8 + (size_t)gr * 128 + lid * 8) = make_uint2((unsigned)d0, (unsigned)d1);
        }
    }
}

// 2) per-bucket counting sort, 512 threads/block (8 waves — halves every
//    strided pass vs the 256-thread version; scan keeps t<NB guards with
//    all threads reaching every barrier).
__global__ __launch_bounds__(512) void k_sort(const unsigned int* __restrict__ ebuf,
                                              const int* __restrict__ bcur,
                                              int* __restrict__ csr_src,
                                              int* __restrict__ rowptr,
                                              int* __restrict__ deg,
                                              float* __restrict__ dinv) {
    __shared__ int hist[NB], off[NB], cur[NB];
    __shared__ int stage[CAP];
    const int t = threadIdx.x;
    const int b = blockIdx.x;
    const int cnt = bcur[b * PAD];
    const int ebeg = b * CAP;
    const int nbase = b * BW;
    if (t < NB) { hist[t] = 0; cur[t] = 0; }
    __syncthreads();
    for (int i = t; i < cnt; i += 512)
        atomicAdd(&hist[ebuf[ebeg + i] >> 17], 1);
    __syncthreads();
    int v = 0;
    if (t < NB) { v = hist[t]; off[t] = v; }
    __syncthreads();
    for (int o = 1; o < NB; o <<= 1) {
        int u = (t < NB && t >= o) ? off[t - o] : 0;
        __syncthreads();
        if (t < NB) off[t] += u;
        __syncthreads();
    }
    if (t < NB) {
        int ex = off[t] - v;
        int gn = nbase + t;
        if (t < BW && gn < NN) {
            rowptr[gn] = ebeg + ex;
            deg[gn] = v;
            dinv[gn] = rsqrtf((float)(v + 1));
        }
    }
    __syncthreads();
    if (t < NB) off[t] -= v;                 // off[t] = exclusive prefix
    __syncthreads();
    for (int i = t; i < cnt; i += 512) {
        unsigned int p = ebuf[ebeg + i];
        int l = p >> 17;
        int r = atomicAdd(&cur[l], 1);
        stage[off[l] + r] = (int)(p & 0x1FFFFu);
    }
    __syncthreads();
    for (int i = t; i < cnt; i += 512)
        csr_src[ebeg + i] = stage[i];
}

// 3) aggregation: quarter-wave (16 lanes x 8ch fp8 uint2) owns ONE dst node.
//    Per edge the group issues ONE coalesced 128B h8-row read — gather floor.
//    h8 permuted layout: thread ql's decoded a[j] = actual col (j*16+ql).
//    Per-edge dinv[s]; bias gathered permuted; pooled write un-permutes.
__global__ __launch_bounds__(256) void k_agg(const unsigned char* __restrict__ h8,
                                             const int* __restrict__ csr_src,
                                             const int* __restrict__ rowptr,
                                             const int* __restrict__ deg,
                                             const float* __restrict__ dinv,
                                             const float* __restrict__ b1,
                                             const int* __restrict__ batch,
                                             int* __restrict__ pooled) {
    const int tid = threadIdx.x;
    const int qg = tid >> 4, ql = tid & 15;
    const int n = blockIdx.x * 16 + qg;      // NN = 3125*16, no tail
    __shared__ float vals[16][128];
    __shared__ int bts[16];
    if (ql == 0) bts[qg] = batch[n];
    const float dd = dinv[n];
    const int beg = rowptr[n];
    const int end = beg + deg[n];
    const int c = ql * 8;
    float a[8];
#pragma unroll
    for (int j = 0; j < 8; ++j) a[j] = 0.f;
#pragma unroll 4
    for (int i = beg; i < end; ++i) {
        int s = csr_src[i];
        float ds = dinv[s];
        uint2 v = *(const uint2*)(h8 + (size_t)s * 128 + c);
        f32x2 f0 = __builtin_amdgcn_cvt_pk_f32_fp8((int)v.x, false);
        f32x2 f1 = __builtin_amdgcn_cvt_pk_f32_fp8((int)v.x, true);
        f32x2 f2 = __builtin_amdgcn_cvt_pk_f32_fp8((int)v.y, false);
        f32x2 f3 = __builtin_amdgcn_cvt_pk_f32_fp8((int)v.y, true);
        a[0] = fmaf(ds, f0.x, a[0]); a[1] = fmaf(ds, f0.y, a[1]);
        a[2] = fmaf(ds, f1.x, a[2]); a[3] = fmaf(ds, f1.y, a[3]);
        a[4] = fmaf(ds, f2.x, a[4]); a[5] = fmaf(ds, f2.y, a[5]);
        a[6] = fmaf(ds, f3.x, a[6]); a[7] = fmaf(ds, f3.y, a[7]);
    }
    {
        // self loop: + dinv[n]*h[n], whole sum scaled by dinv[n]
        uint2 hv = *(const uint2*)(h8 + (size_t)n * 128 + c);
        f32x2 f0 = __builtin_amdgcn_cvt_pk_f32_fp8((int)hv.x, false);
        f32x2 f1 = __builtin_amdgcn_cvt_pk_f32_fp8((int)hv.x, true);
        f32x2 f2 = __builtin_amdgcn_cvt_pk_f32_fp8((int)hv.y, false);
        f32x2 f3 = __builtin_amdgcn_cvt_pk_f32_fp8((int)hv.y, true);
        float bb[8];
#pragma unroll
        for (int j = 0; j < 8; ++j) bb[j] = b1[j * 16 + ql];
        float r0 = fmaxf(dd * fmaf(dd, f0.x, a[0]) + bb[0], 0.f);
        float r1 = fmaxf(dd * fmaf(dd, f0.y, a[1]) + bb[1], 0.f);
        float r2 = fmaxf(dd * fmaf(dd, f1.x, a[2]) + bb[2], 0.f);
        float r3 = fmaxf(dd * fmaf(dd, f1.y, a[3]) + bb[3], 0.f);
        float r4 = fmaxf(dd * fmaf(dd, f2.x, a[4]) + bb[4], 0.f);
        float r5 = fmaxf(dd * fmaf(dd, f2.y, a[5]) + bb[5], 0.f);
        float r6 = fmaxf(dd * fmaf(dd, f3.x, a[6]) + bb[6], 0.f);
        float r7 = fmaxf(dd * fmaf(dd, f3.y, a[7]) + bb[7], 0.f);
        *(float4*)&vals[qg][c] = make_float4(r0, r1, r2, r3);
        *(float4*)&vals[qg][c + 4] = make_float4(r4, r5, r6, r7);
    }
    __syncthreads();
    if (tid < 128) {
        const int pcol = ((tid & 7) << 4) | (tid >> 3);  // un-permute channel
        float m = vals[0][tid];
        int cur = bts[0];
#pragma unroll
        for (int ww = 1; ww < 16; ++ww) {
            if (bts[ww] != cur) {
                atomicMax(&pooled[cur * 128 + pcol], __float_as_int(m));
                cur = bts[ww];
                m = vals[ww][tid];
            } else {
                m = fmaxf(m, vals[ww][tid]);
            }
        }
        atomicMax(&pooled[cur * 128 + pcol], __float_as_int(m));
    }
}

// 4) out = relu(pooled @ W2 + b2)
__global__ __launch_bounds__(256) void k_gemm2(const float* __restrict__ pooled,
                                               const float* __restrict__ W2,
                                               const float* __restrict__ b2,
                                               float* __restrict__ out) {
    const int tid = threadIdx.x;
    const int row = blockIdx.x * 4 + (tid >> 6);
    const int col = tid & 63;
    const float* p = pooled + row * 128;
    float acc = b2[col];
    for (int k = 0; k < 128; ++k) acc += p[k] * W2[k * 64 + col];
    out[row * 64 + col] = fmaxf(acc, 0.f);
}

extern "C" void kernel_launch(void* const* d_in, const int* in_sizes, int n_in,
                              void* d_out, int out_size, void* d_ws, size_t ws_size,
                              hipStream_t stream) {
    const float* x     = (const float*)d_in[0];
    const int*   ei    = (const int*)d_in[1];   // [2, NE]: src row then dst row
    const int*   batch = (const int*)d_in[2];
    const float* W1    = (const float*)d_in[3];
    const float* b1    = (const float*)d_in[4];
    const float* W2    = (const float*)d_in[5];
    const float* b2    = (const float*)d_in[6];
    float* out = (float*)d_out;

    // ws layout (int units) — round-12 verified best (131.1 us):
    // [zeroed: pooled NG*128 | bcur NB*PAD] rowptr NN | deg NN | dinv NN |
    // csr_src NB*CAP | ebuf NB*CAP | h8 NN*128 bytes
    int*   pooled  = (int*)d_ws;
    int*   bcur    = pooled + (size_t)NG * 128;
    int*   rowptr  = bcur + NB * PAD;
    int*   deg     = rowptr + NN;
    float* dinv    = (float*)(deg + NN);
    int*   csr_src = (int*)(dinv + NN);
    unsigned int* ebuf = (unsigned int*)(csr_src + (size_t)NB * CAP);
    unsigned char* h8  = (unsigned char*)(ebuf + (size_t)NB * CAP);

    size_t zbytes = ((size_t)NG * 128 + NB * PAD) * 4;
    hipMemsetAsync(d_ws, 0, zbytes, stream);

    const int* srcv = ei;
    const int* dstv = ei + NE;

    k_front<<<NGEMM + NBIN, 512, 0, stream>>>(x, W1, h8, srcv, dstv, bcur, ebuf);
    k_sort<<<NB, 512, 0, stream>>>(ebuf, bcur, csr_src, rowptr, deg, dinv);
    k_agg<<<NN / 16, 256, 0, stream>>>(h8, csr_src, rowptr, deg, dinv, b1, batch, pooled);
    k_gemm2<<<NG / 4, 256, 0, stream>>>((const float*)pooled, W2, b2, out);
}